// Round 1
// baseline (77.374 us; speedup 1.0000x reference)
//
#include <hip/hip_runtime.h>

#define N_ROWS 128
#define IN_DIM 1024
#define OUT_DIM 1024

// out[n,o] = max_k(w[o,k] + x[n,k]) + bias[o]
//
// wave tile: 8 n x 8 o. k is split 8 ways across lanes: lane = og*8 + g,
// og = o offset (0..7), g = k phase (0..7). Per load step t, lane handles
// float4 index kq = t*8+g, i.e. k = t*32 + g*4 .. +3. Lanes 0..7 (same o,
// g=0..7) read 128 B contiguous of the w row -> coalesced. x loads touch one
// 128 B segment per n for the whole wave (8-lane broadcast per float4).
// Epilogue: butterfly max over g (xor 1,2,4), g==0 lanes write out.
//
// block = 256 threads = 4 waves in a 2x2 (n,o) arrangement -> 16n x 16o tile
// grid = (128/16) * (1024/16) = 512 blocks -> 2048 waves, 2 waves/SIMD.

__global__ __launch_bounds__(256, 2)
void tropical_linear_kernel(const float* __restrict__ x,
                            const float* __restrict__ w,
                            const float* __restrict__ bias,
                            float* __restrict__ out) {
    const int tid  = threadIdx.x;
    const int wid  = tid >> 6;       // wave 0..3
    const int lane = tid & 63;
    const int g    = lane & 7;       // k phase 0..7
    const int og   = lane >> 3;      // o offset 0..7

    const int bn = blockIdx.x >> 6;  // 8 n-blocks
    const int bo = blockIdx.x & 63;  // 64 o-blocks
    const int n0 = bn * 16 + (wid >> 1) * 8;
    const int o0 = bo * 16 + (wid & 1) * 8;
    const int o  = o0 + og;

    float acc[8];
#pragma unroll
    for (int j = 0; j < 8; ++j) acc[j] = -3.4e38f;

    const float4* __restrict__ wrow = (const float4*)(w + (size_t)o * IN_DIM);
    const float4* __restrict__ x4   = (const float4*)x;
    const int xrow_q = IN_DIM / 4;   // float4 per row

#pragma unroll 2
    for (int t = 0; t < 32; ++t) {
        const int kq = t * 8 + g;
        const float4 wv = wrow[kq];
#pragma unroll
        for (int j = 0; j < 8; ++j) {
            const float4 xv = x4[(size_t)(n0 + j) * xrow_q + kq];
            float m0 = fmaxf(wv.x + xv.x, wv.y + xv.y);
            float m1 = fmaxf(wv.z + xv.z, wv.w + xv.w);
            acc[j] = fmaxf(acc[j], fmaxf(m0, m1));
        }
    }

    // reduce across the 8 k-phases (lanes differing in bits 0..2)
#pragma unroll
    for (int j = 0; j < 8; ++j) {
        float v = acc[j];
        v = fmaxf(v, __shfl_xor(v, 1, 64));
        v = fmaxf(v, __shfl_xor(v, 2, 64));
        v = fmaxf(v, __shfl_xor(v, 4, 64));
        acc[j] = v;
    }

    if (g == 0) {
        const float b = bias[o];
#pragma unroll
        for (int j = 0; j < 8; ++j) {
            out[(size_t)(n0 + j) * OUT_DIM + o] = acc[j] + b;
        }
    }
}

extern "C" void kernel_launch(void* const* d_in, const int* in_sizes, int n_in,
                              void* d_out, int out_size, void* d_ws, size_t ws_size,
                              hipStream_t stream) {
    const float* x    = (const float*)d_in[0];   // [128,1024]
    const float* w    = (const float*)d_in[1];   // [1024,1024]
    const float* bias = (const float*)d_in[2];   // [1024]
    float* out = (float*)d_out;                  // [128,1024]

    dim3 grid(512);
    dim3 block(256);
    hipLaunchKernelGGL(tropical_linear_kernel, grid, block, 0, stream, x, w, bias, out);
}

// Round 2
// 69.927 us; speedup vs baseline: 1.1065x; 1.1065x over previous
//
#include <hip/hip_runtime.h>

#define N_ROWS 128
#define IN_DIM 1024
#define OUT_DIM 1024

// out[n,o] = max_k(w[o,k] + x[n,k]) + bias[o]   (tropical matmul)
//
// Block: 256 threads = 4 waves. Block tile: 8 n x 32 o.
//   - x tile (8 rows x 4 KB = 32 KB) staged in LDS once, shared by all 4
//     o-waves -> K-loop has ONE global load/iter (w stream).
// Wave tile: 8 n x 8 o, K split 8-way across lanes: lane = og*8 + g.
//   Per t, lane handles float4 kq = t*8+g. w lanes 0..7 (g) read 128 B
//   contiguous per o-row (coalesced). x read from LDS: 128 B distinct +
//   8-way og-broadcast (broadcast free).
// w stream: explicit 4-deep register prefetch so ~4 loads stay in flight
//   across 192 VALU cycles of compute.
// Epilogue: butterfly max over g (xor 1,2,4), g==0 lanes write out.
// Grid: 16 n-blocks x 32 o-blocks = 512 blocks, 2 blocks/CU.

__global__ __launch_bounds__(256, 2)
void tropical_linear_kernel(const float* __restrict__ x,
                            const float* __restrict__ w,
                            const float* __restrict__ bias,
                            float* __restrict__ out) {
    __shared__ float4 xs[8 * 256];   // 8 n-rows x 256 float4 = 32 KB

    const int tid  = threadIdx.x;
    const int wid  = tid >> 6;       // wave 0..3
    const int lane = tid & 63;
    const int g    = lane & 7;       // k phase 0..7
    const int og   = lane >> 3;      // o offset 0..7

    const int bn = blockIdx.x >> 5;  // 16 n-blocks
    const int bo = blockIdx.x & 31;  // 32 o-blocks
    const int n0 = bn * 8;
    const int o  = bo * 32 + wid * 8 + og;

    const float4* __restrict__ x4 = (const float4*)x;

    // ---- stage x tile: 2048 float4, 8 per thread, coalesced ----
#pragma unroll
    for (int i = 0; i < 8; ++i) {
        const int idx = tid + i * 256;
        const int r = idx >> 8, c = idx & 255;
        xs[idx] = x4[(size_t)(n0 + r) * 256 + c];
    }
    __syncthreads();

    float acc[8];
#pragma unroll
    for (int j = 0; j < 8; ++j) acc[j] = -3.4e38f;

    const float4* __restrict__ wr = (const float4*)(w + (size_t)o * IN_DIM);

    // ---- 4-deep w prefetch pipeline ----
    float4 wb[4];
#pragma unroll
    for (int i = 0; i < 4; ++i) wb[i] = wr[i * 8 + g];

    for (int tt = 0; tt < 8; ++tt) {
        float4 wc[4];
#pragma unroll
        for (int i = 0; i < 4; ++i) wc[i] = wb[i];
        if (tt < 7) {
#pragma unroll
            for (int i = 0; i < 4; ++i) wb[i] = wr[(tt + 1) * 32 + i * 8 + g];
        }
#pragma unroll
        for (int i = 0; i < 4; ++i) {
            const int kq = tt * 32 + i * 8 + g;
#pragma unroll
            for (int j = 0; j < 8; ++j) {
                const float4 xv = xs[j * 256 + kq];
                const float s0 = wc[i].x + xv.x;
                const float s1 = wc[i].y + xv.y;
                const float s2 = wc[i].z + xv.z;
                const float s3 = wc[i].w + xv.w;
                // max3(s0,s1,s2) then max3(m, s3, acc): 2 x v_max3_f32
                const float m = fmaxf(fmaxf(s0, s1), s2);
                acc[j] = fmaxf(fmaxf(m, s3), acc[j]);
            }
        }
    }

    // ---- reduce across the 8 k-phases (lane bits 0..2) ----
#pragma unroll
    for (int j = 0; j < 8; ++j) {
        float v = acc[j];
        v = fmaxf(v, __shfl_xor(v, 1, 64));
        v = fmaxf(v, __shfl_xor(v, 2, 64));
        v = fmaxf(v, __shfl_xor(v, 4, 64));
        acc[j] = v;
    }

    if (g == 0) {
        const float b = bias[o];
#pragma unroll
        for (int j = 0; j < 8; ++j) {
            out[(size_t)(n0 + j) * OUT_DIM + o] = acc[j] + b;
        }
    }
}

extern "C" void kernel_launch(void* const* d_in, const int* in_sizes, int n_in,
                              void* d_out, int out_size, void* d_ws, size_t ws_size,
                              hipStream_t stream) {
    const float* x    = (const float*)d_in[0];   // [128,1024]
    const float* w    = (const float*)d_in[1];   // [1024,1024]
    const float* bias = (const float*)d_in[2];   // [1024]
    float* out = (float*)d_out;                  // [128,1024]

    dim3 grid(512);
    dim3 block(256);
    hipLaunchKernelGGL(tropical_linear_kernel, grid, block, 0, stream, x, w, bias, out);
}

// Round 3
// 66.878 us; speedup vs baseline: 1.1569x; 1.0456x over previous
//
#include <hip/hip_runtime.h>

#define N_ROWS 128
#define IN_DIM 1024
#define OUT_DIM 1024

// out[n,o] = max_k(w[o,k] + x[n,k]) + bias[o]   (tropical matmul)
//
// Wave tile: 8n x 4o, K split 16-way across lanes: lane = og*16 + g,
//   g = k-phase 0..15, og = o offset 0..3. Per step, lane reads float4
//   kq = t*16+g -> lanes g=0..15 cover 256 B contiguous per o-row (coalesced,
//   4 o-rows = 1 KB per w instruction).
// Block: 256 threads = 4 waves side-by-side in o -> tile 8n x 16o.
//   x tile (8 rows x 4 KB = 32 KB) staged once in LDS, shared by all waves.
// Grid: 16 n-blocks x 64 o-blocks = 1024 blocks -> 4 blocks/CU,
//   16 waves/CU (2x R2) for latency hiding. LDS 4x32 = 128 KB/CU <= 160.
// w stream: 4-deep register prefetch per super-iteration (4 tt each).
// Epilogue: butterfly max over g (xor 1,2,4,8), g==0 lanes write out.

__global__ __launch_bounds__(256, 4)
void tropical_linear_kernel(const float* __restrict__ x,
                            const float* __restrict__ w,
                            const float* __restrict__ bias,
                            float* __restrict__ out) {
    __shared__ float4 xs[8 * 256];   // 32 KB

    const int tid  = threadIdx.x;
    const int wid  = tid >> 6;       // wave 0..3
    const int lane = tid & 63;
    const int g    = lane & 15;      // k phase 0..15
    const int og   = lane >> 4;      // o offset 0..3

    const int bn = blockIdx.x >> 6;  // 16 n-blocks
    const int bo = blockIdx.x & 63;  // 64 o-blocks (same-bo -> same XCD: 64%8==0)
    const int n0 = bn * 8;
    const int o  = bo * 16 + wid * 4 + og;

    const float4* __restrict__ x4 = (const float4*)x;

    // ---- stage x tile: 2048 float4, 8 per thread, coalesced ----
#pragma unroll
    for (int i = 0; i < 8; ++i) {
        const int idx = tid + i * 256;
        const int r = idx >> 8, c = idx & 255;
        xs[idx] = x4[(size_t)(n0 + r) * 256 + c];
    }
    __syncthreads();

    float acc[8];
#pragma unroll
    for (int j = 0; j < 8; ++j) acc[j] = -3.4e38f;

    const float4* __restrict__ wr = (const float4*)(w + (size_t)o * IN_DIM);

    // ---- 4-deep w prefetch; 4 super-iters x 4 tt = 16 steps (K=1024) ----
    float4 wb[4];
#pragma unroll
    for (int i = 0; i < 4; ++i) wb[i] = wr[i * 16 + g];

    for (int ss = 0; ss < 4; ++ss) {
        float4 wc[4];
#pragma unroll
        for (int i = 0; i < 4; ++i) wc[i] = wb[i];
        if (ss < 3) {
#pragma unroll
            for (int i = 0; i < 4; ++i) wb[i] = wr[(ss + 1) * 64 + i * 16 + g];
        }
#pragma unroll
        for (int i = 0; i < 4; ++i) {
            const int kq = ss * 64 + i * 16 + g;
#pragma unroll
            for (int j = 0; j < 8; ++j) {
                const float4 xv = xs[j * 256 + kq];
                const float s0 = wc[i].x + xv.x;
                const float s1 = wc[i].y + xv.y;
                const float s2 = wc[i].z + xv.z;
                const float s3 = wc[i].w + xv.w;
                const float m = fmaxf(fmaxf(s0, s1), s2);   // v_max3
                acc[j] = fmaxf(fmaxf(m, s3), acc[j]);       // v_max3
            }
        }
    }

    // ---- reduce across the 16 k-phases (lane bits 0..3) ----
#pragma unroll
    for (int j = 0; j < 8; ++j) {
        float v = acc[j];
        v = fmaxf(v, __shfl_xor(v, 1, 64));
        v = fmaxf(v, __shfl_xor(v, 2, 64));
        v = fmaxf(v, __shfl_xor(v, 4, 64));
        v = fmaxf(v, __shfl_xor(v, 8, 64));
        acc[j] = v;
    }

    if (g == 0) {
        const float b = bias[o];
#pragma unroll
        for (int j = 0; j < 8; ++j) {
            out[(size_t)(n0 + j) * OUT_DIM + o] = acc[j] + b;
        }
    }
}

extern "C" void kernel_launch(void* const* d_in, const int* in_sizes, int n_in,
                              void* d_out, int out_size, void* d_ws, size_t ws_size,
                              hipStream_t stream) {
    const float* x    = (const float*)d_in[0];   // [128,1024]
    const float* w    = (const float*)d_in[1];   // [1024,1024]
    const float* bias = (const float*)d_in[2];   // [1024]
    float* out = (float*)d_out;                  // [128,1024]

    dim3 grid(1024);
    dim3 block(256);
    hipLaunchKernelGGL(tropical_linear_kernel, grid, block, 0, stream, x, w, bias, out);
}